// Round 1
// baseline (428.033 us; speedup 1.0000x reference)
//
#include <hip/hip_runtime.h>
#include <cstddef>
#include <cstdint>

#define BATCH 16
#define CHAN 3
#define HH 128
#define WW 128
#define PATCHK 7
#define HP 122                 // (128-7)/1 + 1
#define PDIM 147               // 3*7*7
#define NSAMP 4096
#define NPROJ 128
#define IMG_PIX (CHAN*HH*WW)   // 49152
#define TOT_PIX (BATCH*IMG_PIX)
#define COUNT_D ((double)BATCH*HP*HP*PDIM)   // 35007168

// ---------------- kernel A: weighted pixel sums (patch-tensor mean) -------
// pixel (i,j) appears in w(i)*w(j) patches; mean = weighted_sum / (B*L*PDIM)
__global__ __launch_bounds__(256)
void k_wsum(const float* __restrict__ x, const float* __restrict__ y,
            double* __restrict__ outx, double* __restrict__ outy) {
  float sx = 0.f, sy = 0.f;
  const int stride = gridDim.x * blockDim.x;
  for (int e = blockIdx.x * blockDim.x + threadIdx.x; e < TOT_PIX; e += stride) {
    int j = e & (WW - 1);
    int i = (e >> 7) & (HH - 1);
    int wi = min(i, HP - 1) - max(0, i - (PATCHK - 1)) + 1;
    int wj = min(j, HP - 1) - max(0, j - (PATCHK - 1)) + 1;
    float w = (float)(wi * wj);
    sx = fmaf(x[e], w, sx);
    sy = fmaf(y[e], w, sy);
  }
  __shared__ float rx[256], ry[256];
  const int tid = threadIdx.x;
  rx[tid] = sx; ry[tid] = sy;
  __syncthreads();
  for (int off = 128; off; off >>= 1) {
    if (tid < off) { rx[tid] += rx[tid + off]; ry[tid] += ry[tid + off]; }
    __syncthreads();
  }
  if (tid == 0) { outx[blockIdx.x] = (double)rx[0]; outy[blockIdx.x] = (double)ry[0]; }
}

// final mean difference (deterministic single-block reduce of 256 partials)
__global__ void k_meandiff(const double* __restrict__ px, const double* __restrict__ py,
                           double* __restrict__ dmean) {
  __shared__ double s[256];
  const int tid = threadIdx.x;
  s[tid] = px[tid] - py[tid];
  __syncthreads();
  for (int off = 128; off; off >>= 1) {
    if (tid < off) s[tid] += s[tid + off];
    __syncthreads();
  }
  if (tid == 0) dmean[0] = s[0] / COUNT_D;
}

// column sums of proj: s_p = sum_d proj[d][p]
__global__ void k_colsum(const float* __restrict__ proj, float* __restrict__ sp) {
  const int p = threadIdx.x;
  float s = 0.f;
  for (int d = 0; d < PDIM; ++d) s += proj[d * NPROJ + p];
  sp[p] = s;
}

// ---------------- kernel B: gather + projection GEMM ----------------------
// per block: one batch b, one image (z), 128-patch tile; A staged in LDS
// [147][132] (K-major rows, padded), B = proj [147*128] in LDS.
// 256 threads, each computes an 8n x 8p register tile over K=147.
// Output layout: dst[(b*128 + p)*4096 + n]  (n contiguous for the sort kernel)
#define TN 128
__global__ __launch_bounds__(256)
void k_proj(const float* __restrict__ x, const float* __restrict__ y,
            const float* __restrict__ proj,
            const int* __restrict__ idx_x, const int* __restrict__ idx_y,
            float* __restrict__ PX, float* __restrict__ PY) {
  __shared__ float Bs[PDIM * NPROJ];       // 75264 B
  __shared__ float As[PDIM][TN + 4];       // 77616 B (row stride 132 words, 16B-aligned)

  const int z = blockIdx.z;
  const float* im = z ? y : x;
  const int* idx = z ? idx_y : idx_x;
  float* dst = z ? PY : PX;
  const int b = blockIdx.y;
  const int nbase = blockIdx.x * TN;
  const int tid = threadIdx.x;

  for (int q = tid; q < PDIM * NPROJ; q += 256) Bs[q] = proj[q];

  const float* imb = im + b * IMG_PIX;
  for (int e = tid; e < TN * PDIM; e += 256) {
    int n = e / PDIM;                  // const-div -> magic mul
    int d = e - n * PDIM;
    int l = idx[nbase + n];
    int h0 = l / HP;
    int w0 = l - h0 * HP;
    int c  = d / 49;                   // channel-major patch layout: d = c*49 + kh*7 + kw
    int r  = d - c * 49;
    int kh = r / 7;
    int kw = r - kh * 7;
    As[d][n] = imb[(c * HH + (h0 + kh)) * WW + (w0 + kw)];
  }
  __syncthreads();

  const int n0 = (tid >> 4) * 8;
  const int p0 = (tid & 15) * 8;
  float acc[8][8];
#pragma unroll
  for (int u = 0; u < 8; ++u)
#pragma unroll
    for (int v = 0; v < 8; ++v) acc[u][v] = 0.f;

  for (int k = 0; k < PDIM; ++k) {
    const float4 a0 = *(const float4*)&As[k][n0];
    const float4 a1 = *(const float4*)&As[k][n0 + 4];
    const float4 b0 = *(const float4*)&Bs[k * NPROJ + p0];
    const float4 b1 = *(const float4*)&Bs[k * NPROJ + p0 + 4];
    const float av[8] = {a0.x, a0.y, a0.z, a0.w, a1.x, a1.y, a1.z, a1.w};
    const float bv[8] = {b0.x, b0.y, b0.z, b0.w, b1.x, b1.y, b1.z, b1.w};
#pragma unroll
    for (int u = 0; u < 8; ++u)
#pragma unroll
      for (int v = 0; v < 8; ++v)
        acc[u][v] = fmaf(av[u], bv[v], acc[u][v]);
  }

#pragma unroll
  for (int v = 0; v < 8; ++v) {
    float* o = dst + (size_t)(b * NPROJ + p0 + v) * NSAMP + nbase + n0;
    *(float4*)(o)     = make_float4(acc[0][v], acc[1][v], acc[2][v], acc[3][v]);
    *(float4*)(o + 4) = make_float4(acc[4][v], acc[5][v], acc[6][v], acc[7][v]);
  }
}

// ---------------- kernel C: per-(b,p) bitonic sort of both arrays + |diff| -
__global__ __launch_bounds__(512)
void k_sortdiff(const float* __restrict__ PX, const float* __restrict__ PY,
                const float* __restrict__ sp, const double* __restrict__ dmean,
                float* __restrict__ bsum) {
  __shared__ float ax[NSAMP];
  __shared__ float ay[NSAMP];
  const int bp = blockIdx.x;          // b*128 + p
  const int p = bp & (NPROJ - 1);
  const int tid = threadIdx.x;

  const float4* rx = (const float4*)(PX + (size_t)bp * NSAMP);
  const float4* ry = (const float4*)(PY + (size_t)bp * NSAMP);
  for (int q = tid; q < NSAMP / 4; q += 512) {
    ((float4*)ax)[q] = rx[q];
    ((float4*)ay)[q] = ry[q];
  }
  __syncthreads();

  for (int k = 2; k <= NSAMP; k <<= 1) {
    for (int j = k >> 1; j > 0; j >>= 1) {
#pragma unroll
      for (int r = 0; r < NSAMP / 2 / 512; ++r) {   // 4 pairs/thread/stage
        int q = tid + r * 512;
        int i = ((q & ~(j - 1)) << 1) | (q & (j - 1));
        int ix = i | j;
        bool up = (i & k) == 0;
        float a = ax[i], b2 = ax[ix];
        float lo = fminf(a, b2), hi = fmaxf(a, b2);
        ax[i] = up ? lo : hi; ax[ix] = up ? hi : lo;
        float c = ay[i], d2 = ay[ix];
        float lo2 = fminf(c, d2), hi2 = fmaxf(c, d2);
        ay[i] = up ? lo2 : hi2; ay[ix] = up ? hi2 : lo2;
      }
      __syncthreads();
    }
  }

  const float delta = (float)(dmean[0]) * sp[p];
  float s = 0.f;
  for (int q = tid; q < NSAMP; q += 512) s += fabsf(ax[q] - ay[q] - delta);

  __shared__ float red[512];
  red[tid] = s;
  __syncthreads();
  for (int off = 256; off; off >>= 1) {
    if (tid < off) red[tid] += red[tid + off];
    __syncthreads();
  }
  if (tid == 0) bsum[bp] = red[0];
}

// ---------------- kernel D: deterministic final reduce --------------------
__global__ void k_final(const float* __restrict__ bsum, float* __restrict__ out) {
  __shared__ double s[256];
  const int tid = threadIdx.x;
  double v = 0.0;
  for (int q = tid; q < BATCH * NPROJ; q += 256) v += (double)bsum[q];
  s[tid] = v;
  __syncthreads();
  for (int off = 128; off; off >>= 1) {
    if (tid < off) s[tid] += s[tid + off];
    __syncthreads();
  }
  if (tid == 0) out[0] = (float)(s[0] / ((double)NSAMP * NPROJ * BATCH));
}

extern "C" void kernel_launch(void* const* d_in, const int* in_sizes, int n_in,
                              void* d_out, int out_size, void* d_ws, size_t ws_size,
                              hipStream_t stream) {
  const float* x    = (const float*)d_in[0];
  const float* y    = (const float*)d_in[1];
  const float* proj = (const float*)d_in[2];
  const int* idx_x  = (const int*)d_in[3];
  const int* idx_y  = (const int*)d_in[4];
  float* out = (float*)d_out;

  char* ws = (char*)d_ws;
  double* pAx   = (double*)(ws + 0);        // 256 doubles
  double* pAy   = (double*)(ws + 2048);     // 256 doubles
  double* dmean = (double*)(ws + 4096);     // 1 double
  float*  sp    = (float*)(ws + 4160);      // 128 floats
  float*  bsum  = (float*)(ws + 8192);      // 2048 floats
  float*  PX    = (float*)(ws + 16384);     // 16*128*4096 floats
  float*  PY    = PX + (size_t)BATCH * NPROJ * NSAMP;

  const size_t need = 16384 + 2ull * BATCH * NPROJ * NSAMP * sizeof(float);
  if (ws_size < need) return;  // fail loudly (output stays zero) rather than OOB

  k_wsum    <<<256, 256, 0, stream>>>(x, y, pAx, pAy);
  k_meandiff<<<1, 256, 0, stream>>>(pAx, pAy, dmean);
  k_colsum  <<<1, NPROJ, 0, stream>>>(proj, sp);
  k_proj    <<<dim3(NSAMP / TN, BATCH, 2), 256, 0, stream>>>(x, y, proj, idx_x, idx_y, PX, PY);
  k_sortdiff<<<BATCH * NPROJ, 512, 0, stream>>>(PX, PY, sp, dmean, bsum);
  k_final   <<<1, 256, 0, stream>>>(bsum, out);
}

// Round 2
// 306.508 us; speedup vs baseline: 1.3965x; 1.3965x over previous
//
#include <hip/hip_runtime.h>
#include <cstddef>
#include <cstdint>

#define BATCH 16
#define CHAN 3
#define HH 128
#define WW 128
#define PATCHK 7
#define HP 122                 // (128-7)/1 + 1
#define PDIM 147               // 3*7*7
#define NSAMP 4096
#define NPROJ 128
#define IMG_PIX (CHAN*HH*WW)   // 49152
#define TOT_PIX (BATCH*IMG_PIX)
#define COUNT_D ((double)BATCH*HP*HP*PDIM)   // 35007168

// ---------------- kernel A: weighted pixel sums (patch-tensor mean) -------
__global__ __launch_bounds__(256)
void k_wsum(const float* __restrict__ x, const float* __restrict__ y,
            double* __restrict__ outx, double* __restrict__ outy) {
  float sx = 0.f, sy = 0.f;
  const int stride = gridDim.x * blockDim.x;
  for (int e = blockIdx.x * blockDim.x + threadIdx.x; e < TOT_PIX; e += stride) {
    int j = e & (WW - 1);
    int i = (e >> 7) & (HH - 1);
    int wi = min(i, HP - 1) - max(0, i - (PATCHK - 1)) + 1;
    int wj = min(j, HP - 1) - max(0, j - (PATCHK - 1)) + 1;
    float w = (float)(wi * wj);
    sx = fmaf(x[e], w, sx);
    sy = fmaf(y[e], w, sy);
  }
  __shared__ float rx[256], ry[256];
  const int tid = threadIdx.x;
  rx[tid] = sx; ry[tid] = sy;
  __syncthreads();
  for (int off = 128; off; off >>= 1) {
    if (tid < off) { rx[tid] += rx[tid + off]; ry[tid] += ry[tid + off]; }
    __syncthreads();
  }
  if (tid == 0) { outx[blockIdx.x] = (double)rx[0]; outy[blockIdx.x] = (double)ry[0]; }
}

__global__ void k_meandiff(const double* __restrict__ px, const double* __restrict__ py,
                           double* __restrict__ dmean) {
  __shared__ double s[256];
  const int tid = threadIdx.x;
  s[tid] = px[tid] - py[tid];
  __syncthreads();
  for (int off = 128; off; off >>= 1) {
    if (tid < off) s[tid] += s[tid + off];
    __syncthreads();
  }
  if (tid == 0) dmean[0] = s[0] / COUNT_D;
}

__global__ void k_colsum(const float* __restrict__ proj, float* __restrict__ sp) {
  const int p = threadIdx.x;
  float s = 0.f;
  for (int d = 0; d < PDIM; ++d) s += proj[d * NPROJ + p];
  sp[p] = s;
}

// ---------------- kernel B: gather + projection GEMM ----------------------
// 256 threads = 4 waves. Wave w owns p-block [32w, 32w+32): proj reads are
// wave-uniform -> scalar loads (SGPR), feed v_fma directly. Each lane owns
// 2 patches (n = 2*lane) -> one ds_read_b64 per k. LDS = A only (76.4 KB)
// -> 2 blocks/CU. Output layout dst[(b*128+p)*4096 + n].
#define TM 128
#define APAD 2                // stride 130 words: b64 reads conflict-free, 8B aligned
__global__ __launch_bounds__(256)
void k_proj(const float* __restrict__ x, const float* __restrict__ y,
            const float* __restrict__ proj,
            const int* __restrict__ idx_x, const int* __restrict__ idx_y,
            float* __restrict__ PX, float* __restrict__ PY) {
  __shared__ float As[PDIM][TM + APAD];   // 147*130*4 = 76440 B

  const int z = blockIdx.z;
  const float* im = z ? y : x;
  const int* idx = z ? idx_y : idx_x;
  float* dst = z ? PY : PX;
  const int b = blockIdx.y;
  const int nbase = blockIdx.x * TM;
  const int tid = threadIdx.x;

  const float* imb = im + b * IMG_PIX;
  for (int e = tid; e < TM * PDIM; e += 256) {
    int n = e / PDIM;
    int d = e - n * PDIM;
    int l = idx[nbase + n];
    int h0 = l / HP;
    int w0 = l - h0 * HP;
    int c  = d / 49;                   // d = c*49 + kh*7 + kw (channel-major)
    int r  = d - c * 49;
    int kh = r / 7;
    int kw = r - kh * 7;
    As[d][n] = imb[(c * HH + h0 + kh) * WW + w0 + kw];
  }
  __syncthreads();

  const int lane = tid & 63;
  const int w = __builtin_amdgcn_readfirstlane(tid >> 6);   // wave id (SGPR)
  const float* bp = proj + w * 32;                          // uniform base
  const int n0 = lane * 2;

  float acc0[32], acc1[32];
#pragma unroll
  for (int pp = 0; pp < 32; ++pp) { acc0[pp] = 0.f; acc1[pp] = 0.f; }

  for (int k = 0; k < PDIM; ++k) {
    const float2 a = *(const float2*)&As[k][n0];
#pragma unroll
    for (int pp = 0; pp < 32; ++pp) {
      const float bv = bp[k * NPROJ + pp];   // wave-uniform -> s_load
      acc0[pp] = fmaf(a.x, bv, acc0[pp]);
      acc1[pp] = fmaf(a.y, bv, acc1[pp]);
    }
  }

#pragma unroll
  for (int pp = 0; pp < 32; ++pp) {
    float* o = dst + (size_t)(b * NPROJ + w * 32 + pp) * NSAMP + nbase + n0;
    *(float2*)o = make_float2(acc0[pp], acc1[pp]);
  }
}

// ---------------- kernel C: register-blocked bitonic sort + |diff| --------
// 512 threads, VT=8 elems/thread/array in registers. j<8: in-register;
// 8<=j<=256: __shfl_xor; j in {512,1024,2048}: LDS exchange (6 stages,
// 12 barriers total). Diff is register-local at the end.
#define CSWAP(a, b, u) { float _lo = fminf(a, b), _hi = fmaxf(a, b); \
                         (a) = (u) ? _lo : _hi; (b) = (u) ? _hi : _lo; }

__global__ __launch_bounds__(512)
void k_sortdiff(const float* __restrict__ PX, const float* __restrict__ PY,
                const float* __restrict__ sp, const double* __restrict__ dmean,
                float* __restrict__ bsum) {
  __shared__ float lx[NSAMP];
  __shared__ float ly[NSAMP];
  __shared__ float red[8];
  const int bp = blockIdx.x;          // b*128 + p
  const int p = bp & (NPROJ - 1);
  const int t = threadIdx.x;
  const int ib = t * 8;               // base element index

  float vx[8], vy[8];
  {
    const float4* rx = (const float4*)(PX + (size_t)bp * NSAMP) + t * 2;
    const float4* ry = (const float4*)(PY + (size_t)bp * NSAMP) + t * 2;
    float4 x0 = rx[0], x1 = rx[1], y0 = ry[0], y1 = ry[1];
    vx[0]=x0.x; vx[1]=x0.y; vx[2]=x0.z; vx[3]=x0.w;
    vx[4]=x1.x; vx[5]=x1.y; vx[6]=x1.z; vx[7]=x1.w;
    vy[0]=y0.x; vy[1]=y0.y; vy[2]=y0.z; vy[3]=y0.w;
    vy[4]=y1.x; vy[5]=y1.y; vy[6]=y1.z; vy[7]=y1.w;
  }

  // ---- phase A: k=2,4,8 fully in-register ----
  {
    const bool u8 = ((t & 1) == 0);
#pragma unroll
    for (int a = 0; a < 2; ++a) {
      float* v = a ? vy : vx;
      // k=2
      CSWAP(v[0], v[1], true);  CSWAP(v[2], v[3], false);
      CSWAP(v[4], v[5], true);  CSWAP(v[6], v[7], false);
      // k=4
      CSWAP(v[0], v[2], true);  CSWAP(v[1], v[3], true);
      CSWAP(v[4], v[6], false); CSWAP(v[5], v[7], false);
      CSWAP(v[0], v[1], true);  CSWAP(v[2], v[3], true);
      CSWAP(v[4], v[5], false); CSWAP(v[6], v[7], false);
      // k=8
      CSWAP(v[0], v[4], u8); CSWAP(v[1], v[5], u8);
      CSWAP(v[2], v[6], u8); CSWAP(v[3], v[7], u8);
      CSWAP(v[0], v[2], u8); CSWAP(v[1], v[3], u8);
      CSWAP(v[4], v[6], u8); CSWAP(v[5], v[7], u8);
      CSWAP(v[0], v[1], u8); CSWAP(v[2], v[3], u8);
      CSWAP(v[4], v[5], u8); CSWAP(v[6], v[7], u8);
    }
  }

  // ---- main bitonic merges k=16..4096 ----
  for (int k = 16; k <= NSAMP; k <<= 1) {
    const bool up = ((ib & k) == 0);   // k=4096 -> 0 -> ascending final merge

    // LDS stages: j in {2048,1024,512} (partner in another wave)
    for (int j = k >> 1; j >= 512; j >>= 1) {
      const int dl = j >> 3;
      ((float4*)lx)[t * 2]     = make_float4(vx[0], vx[1], vx[2], vx[3]);
      ((float4*)lx)[t * 2 + 1] = make_float4(vx[4], vx[5], vx[6], vx[7]);
      ((float4*)ly)[t * 2]     = make_float4(vy[0], vy[1], vy[2], vy[3]);
      ((float4*)ly)[t * 2 + 1] = make_float4(vy[4], vy[5], vy[6], vy[7]);
      __syncthreads();
      const int pt = (t ^ dl) * 2;
      float4 ox0 = ((const float4*)lx)[pt], ox1 = ((const float4*)lx)[pt + 1];
      float4 oy0 = ((const float4*)ly)[pt], oy1 = ((const float4*)ly)[pt + 1];
      const bool keepLo = (((t & dl) == 0) == up);
      float ox[8] = {ox0.x, ox0.y, ox0.z, ox0.w, ox1.x, ox1.y, ox1.z, ox1.w};
      float oy[8] = {oy0.x, oy0.y, oy0.z, oy0.w, oy1.x, oy1.y, oy1.z, oy1.w};
#pragma unroll
      for (int r = 0; r < 8; ++r) {
        vx[r] = keepLo ? fminf(vx[r], ox[r]) : fmaxf(vx[r], ox[r]);
        vy[r] = keepLo ? fminf(vy[r], oy[r]) : fmaxf(vy[r], oy[r]);
      }
      __syncthreads();
    }

    // shuffle stages: 8 <= j <= 256 (partner within wave)
    for (int j = (k >> 1) > 256 ? 256 : (k >> 1); j >= 8; j >>= 1) {
      const int dl = j >> 3;
      const bool keepLo = (((t & dl) == 0) == up);
#pragma unroll
      for (int r = 0; r < 8; ++r) {
        float ox = __shfl_xor(vx[r], dl, 64);
        vx[r] = keepLo ? fminf(vx[r], ox) : fmaxf(vx[r], ox);
        float oy = __shfl_xor(vy[r], dl, 64);
        vy[r] = keepLo ? fminf(vy[r], oy) : fmaxf(vy[r], oy);
      }
    }

    // j = 4,2,1 in-register
#pragma unroll
    for (int a = 0; a < 2; ++a) {
      float* v = a ? vy : vx;
      CSWAP(v[0], v[4], up); CSWAP(v[1], v[5], up);
      CSWAP(v[2], v[6], up); CSWAP(v[3], v[7], up);
      CSWAP(v[0], v[2], up); CSWAP(v[1], v[3], up);
      CSWAP(v[4], v[6], up); CSWAP(v[5], v[7], up);
      CSWAP(v[0], v[1], up); CSWAP(v[2], v[3], up);
      CSWAP(v[4], v[5], up); CSWAP(v[6], v[7], up);
    }
  }

  // ---- diff + reduce (register-local: thread owns elems [8t,8t+8) of both)
  const float delta = (float)(dmean[0]) * sp[p];
  float s = 0.f;
#pragma unroll
  for (int r = 0; r < 8; ++r) s += fabsf(vx[r] - vy[r] - delta);

#pragma unroll
  for (int o = 1; o < 64; o <<= 1) s += __shfl_xor(s, o, 64);
  if ((t & 63) == 0) red[t >> 6] = s;
  __syncthreads();
  if (t == 0) {
    float tot = 0.f;
#pragma unroll
    for (int i = 0; i < 8; ++i) tot += red[i];
    bsum[bp] = tot;
  }
}

// ---------------- kernel D: deterministic final reduce --------------------
__global__ void k_final(const float* __restrict__ bsum, float* __restrict__ out) {
  __shared__ double s[256];
  const int tid = threadIdx.x;
  double v = 0.0;
  for (int q = tid; q < BATCH * NPROJ; q += 256) v += (double)bsum[q];
  s[tid] = v;
  __syncthreads();
  for (int off = 128; off; off >>= 1) {
    if (tid < off) s[tid] += s[tid + off];
    __syncthreads();
  }
  if (tid == 0) out[0] = (float)(s[0] / ((double)NSAMP * NPROJ * BATCH));
}

extern "C" void kernel_launch(void* const* d_in, const int* in_sizes, int n_in,
                              void* d_out, int out_size, void* d_ws, size_t ws_size,
                              hipStream_t stream) {
  const float* x    = (const float*)d_in[0];
  const float* y    = (const float*)d_in[1];
  const float* proj = (const float*)d_in[2];
  const int* idx_x  = (const int*)d_in[3];
  const int* idx_y  = (const int*)d_in[4];
  float* out = (float*)d_out;

  char* ws = (char*)d_ws;
  double* pAx   = (double*)(ws + 0);        // 256 doubles
  double* pAy   = (double*)(ws + 2048);     // 256 doubles
  double* dmean = (double*)(ws + 4096);     // 1 double
  float*  sp    = (float*)(ws + 4160);      // 128 floats
  float*  bsum  = (float*)(ws + 8192);      // 2048 floats
  float*  PX    = (float*)(ws + 16384);     // 16*128*4096 floats
  float*  PY    = PX + (size_t)BATCH * NPROJ * NSAMP;

  const size_t need = 16384 + 2ull * BATCH * NPROJ * NSAMP * sizeof(float);
  if (ws_size < need) return;

  k_wsum    <<<256, 256, 0, stream>>>(x, y, pAx, pAy);
  k_meandiff<<<1, 256, 0, stream>>>(pAx, pAy, dmean);
  k_colsum  <<<1, NPROJ, 0, stream>>>(proj, sp);
  k_proj    <<<dim3(NSAMP / TM, BATCH, 2), 256, 0, stream>>>(x, y, proj, idx_x, idx_y, PX, PY);
  k_sortdiff<<<BATCH * NPROJ, 512, 0, stream>>>(PX, PY, sp, dmean, bsum);
  k_final   <<<1, 256, 0, stream>>>(bsum, out);
}

// Round 3
// 266.312 us; speedup vs baseline: 1.6073x; 1.1509x over previous
//
#include <hip/hip_runtime.h>
#include <cstddef>
#include <cstdint>

#define BATCH 16
#define CHAN 3
#define HH 128
#define WW 128
#define PATCHK 7
#define HP 122                 // (128-7)/1 + 1
#define PDIM 147               // 3*7*7
#define NSAMP 4096
#define NPROJ 128
#define IMG_PIX (CHAN*HH*WW)   // 49152
#define TOT_PIX (BATCH*IMG_PIX)
#define COUNT_D ((double)BATCH*HP*HP*PDIM)   // 35007168

// ---------------- kernel A: weighted pixel sums (patch-tensor mean) -------
__global__ __launch_bounds__(256)
void k_wsum(const float* __restrict__ x, const float* __restrict__ y,
            double* __restrict__ outx, double* __restrict__ outy) {
  float sx = 0.f, sy = 0.f;
  const int stride = gridDim.x * blockDim.x;
  for (int e = blockIdx.x * blockDim.x + threadIdx.x; e < TOT_PIX; e += stride) {
    int j = e & (WW - 1);
    int i = (e >> 7) & (HH - 1);
    int wi = min(i, HP - 1) - max(0, i - (PATCHK - 1)) + 1;
    int wj = min(j, HP - 1) - max(0, j - (PATCHK - 1)) + 1;
    float w = (float)(wi * wj);
    sx = fmaf(x[e], w, sx);
    sy = fmaf(y[e], w, sy);
  }
  __shared__ float rx[256], ry[256];
  const int tid = threadIdx.x;
  rx[tid] = sx; ry[tid] = sy;
  __syncthreads();
  for (int off = 128; off; off >>= 1) {
    if (tid < off) { rx[tid] += rx[tid + off]; ry[tid] += ry[tid + off]; }
    __syncthreads();
  }
  if (tid == 0) { outx[blockIdx.x] = (double)rx[0]; outy[blockIdx.x] = (double)ry[0]; }
}

__global__ void k_meandiff(const double* __restrict__ px, const double* __restrict__ py,
                           double* __restrict__ dmean) {
  __shared__ double s[256];
  const int tid = threadIdx.x;
  s[tid] = px[tid] - py[tid];
  __syncthreads();
  for (int off = 128; off; off >>= 1) {
    if (tid < off) s[tid] += s[tid + off];
    __syncthreads();
  }
  if (tid == 0) dmean[0] = s[0] / COUNT_D;
}

__global__ void k_colsum(const float* __restrict__ proj, float* __restrict__ sp) {
  const int p = threadIdx.x;
  float s = 0.f;
  for (int d = 0; d < PDIM; ++d) s += proj[d * NPROJ + p];
  sp[p] = s;
}

// ---------------- kernel B: gather + projection GEMM ----------------------
// TM=64: LDS 147*65*4 = 38220 B -> 4 blocks/CU. 256 threads = 4 waves.
// Wave w owns p-block [32w,32w+32) (proj reads wave-uniform -> SGPR).
// Lane owns 1 patch: per k = 1 ds_read_b32 (conflict-free) + 32 v_fma.
#define TM 64
#define ASTR (TM + 1)          // 65 words: gather writes stride-65 -> conflict-free
__global__ __launch_bounds__(256)
void k_proj(const float* __restrict__ x, const float* __restrict__ y,
            const float* __restrict__ proj,
            const int* __restrict__ idx_x, const int* __restrict__ idx_y,
            float* __restrict__ PX, float* __restrict__ PY) {
  __shared__ float As[PDIM * ASTR];

  const int z = blockIdx.z;
  const float* im = z ? y : x;
  const int* idx = z ? idx_y : idx_x;
  float* dst = z ? PY : PX;
  const int b = blockIdx.y;
  const int nbase = blockIdx.x * TM;
  const int tid = threadIdx.x;

  const float* imb = im + b * IMG_PIX;
  for (int e = tid; e < TM * PDIM; e += 256) {
    int n = e / PDIM;
    int d = e - n * PDIM;
    int l = idx[nbase + n];
    int h0 = l / HP;
    int w0 = l - h0 * HP;
    int c  = d / 49;                   // d = c*49 + kh*7 + kw (channel-major)
    int r  = d - c * 49;
    int kh = r / 7;
    int kw = r - kh * 7;
    As[d * ASTR + n] = imb[(c * HH + h0 + kh) * WW + w0 + kw];
  }
  __syncthreads();

  const int lane = tid & 63;
  const int w = __builtin_amdgcn_readfirstlane(tid >> 6);   // wave id -> SGPR
  const float* bp = proj + w * 32;                          // wave-uniform base

  float acc[32];
#pragma unroll
  for (int pp = 0; pp < 32; ++pp) acc[pp] = 0.f;

  for (int k = 0; k < PDIM; ++k) {
    const float a = As[k * ASTR + lane];
#pragma unroll
    for (int pp = 0; pp < 32; ++pp)
      acc[pp] = fmaf(a, bp[k * NPROJ + pp], acc[pp]);   // SGPR-fed fma
  }

#pragma unroll
  for (int pp = 0; pp < 32; ++pp)
    dst[(size_t)(b * NPROJ + w * 32 + pp) * NSAMP + nbase + lane] = acc[pp];
}

// ---------------- kernel C: register-blocked bitonic sort + |diff| --------
// 512 threads, 8 elems/thread/array, ALL register-array indices literal
// (no pointer selects -> no scratch). Shuffle distances compile-time.
#define CSWAP(a, b, u) { float _lo = fminf(a, b), _hi = fmaxf(a, b); \
                         (a) = (u) ? _lo : _hi; (b) = (u) ? _hi : _lo; }

// k=2,4,8 network on one 8-element register array
#define PHASEA(v, u8) do { \
  CSWAP(v[0], v[1], true);  CSWAP(v[2], v[3], false); \
  CSWAP(v[4], v[5], true);  CSWAP(v[6], v[7], false); \
  CSWAP(v[0], v[2], true);  CSWAP(v[1], v[3], true);  \
  CSWAP(v[4], v[6], false); CSWAP(v[5], v[7], false); \
  CSWAP(v[0], v[1], true);  CSWAP(v[2], v[3], true);  \
  CSWAP(v[4], v[5], false); CSWAP(v[6], v[7], false); \
  CSWAP(v[0], v[4], u8); CSWAP(v[1], v[5], u8); \
  CSWAP(v[2], v[6], u8); CSWAP(v[3], v[7], u8); \
  CSWAP(v[0], v[2], u8); CSWAP(v[1], v[3], u8); \
  CSWAP(v[4], v[6], u8); CSWAP(v[5], v[7], u8); \
  CSWAP(v[0], v[1], u8); CSWAP(v[2], v[3], u8); \
  CSWAP(v[4], v[5], u8); CSWAP(v[6], v[7], u8); } while (0)

// j=4,2,1 merge on one 8-element register array (direction up)
#define REG3(v, up) do { \
  CSWAP(v[0], v[4], up); CSWAP(v[1], v[5], up); \
  CSWAP(v[2], v[6], up); CSWAP(v[3], v[7], up); \
  CSWAP(v[0], v[2], up); CSWAP(v[1], v[3], up); \
  CSWAP(v[4], v[6], up); CSWAP(v[5], v[7], up); \
  CSWAP(v[0], v[1], up); CSWAP(v[2], v[3], up); \
  CSWAP(v[4], v[5], up); CSWAP(v[6], v[7], up); } while (0)

template <int DL>
__device__ __forceinline__ void shufstage(float (&vx)[8], float (&vy)[8],
                                          int t, bool up) {
  const bool keepLo = (((t & DL) == 0) == up);
#pragma unroll
  for (int r = 0; r < 8; ++r) {
    float ox = __shfl_xor(vx[r], DL, 64);
    vx[r] = keepLo ? fminf(vx[r], ox) : fmaxf(vx[r], ox);
    float oy = __shfl_xor(vy[r], DL, 64);
    vy[r] = keepLo ? fminf(vy[r], oy) : fmaxf(vy[r], oy);
  }
}

// in-wave merge for step K: shuffle stages j=min(K/2,256)..8, then j=4,2,1
template <int K>
__device__ __forceinline__ void merge_inwave(float (&vx)[8], float (&vy)[8],
                                             int t, int ib) {
  const bool up = ((ib & K) == 0);
  if (K / 2 >= 256) shufstage<32>(vx, vy, t, up);
  if (K / 2 >= 128) shufstage<16>(vx, vy, t, up);
  if (K / 2 >= 64)  shufstage<8>(vx, vy, t, up);
  if (K / 2 >= 32)  shufstage<4>(vx, vy, t, up);
  if (K / 2 >= 16)  shufstage<2>(vx, vy, t, up);
  if (K / 2 >= 8)   shufstage<1>(vx, vy, t, up);
  REG3(vx, up);
  REG3(vy, up);
}

__device__ __forceinline__ void lds_stage(float (&vx)[8], float (&vy)[8],
                                          float* lx, float* ly, int t, int dl, bool up) {
  ((float4*)lx)[t * 2]     = make_float4(vx[0], vx[1], vx[2], vx[3]);
  ((float4*)lx)[t * 2 + 1] = make_float4(vx[4], vx[5], vx[6], vx[7]);
  ((float4*)ly)[t * 2]     = make_float4(vy[0], vy[1], vy[2], vy[3]);
  ((float4*)ly)[t * 2 + 1] = make_float4(vy[4], vy[5], vy[6], vy[7]);
  __syncthreads();
  const int pt = (t ^ dl) * 2;
  float4 ox0 = ((const float4*)lx)[pt], ox1 = ((const float4*)lx)[pt + 1];
  float4 oy0 = ((const float4*)ly)[pt], oy1 = ((const float4*)ly)[pt + 1];
  const bool kl = (((t & dl) == 0) == up);
  vx[0] = kl ? fminf(vx[0], ox0.x) : fmaxf(vx[0], ox0.x);
  vx[1] = kl ? fminf(vx[1], ox0.y) : fmaxf(vx[1], ox0.y);
  vx[2] = kl ? fminf(vx[2], ox0.z) : fmaxf(vx[2], ox0.z);
  vx[3] = kl ? fminf(vx[3], ox0.w) : fmaxf(vx[3], ox0.w);
  vx[4] = kl ? fminf(vx[4], ox1.x) : fmaxf(vx[4], ox1.x);
  vx[5] = kl ? fminf(vx[5], ox1.y) : fmaxf(vx[5], ox1.y);
  vx[6] = kl ? fminf(vx[6], ox1.z) : fmaxf(vx[6], ox1.z);
  vx[7] = kl ? fminf(vx[7], ox1.w) : fmaxf(vx[7], ox1.w);
  vy[0] = kl ? fminf(vy[0], oy0.x) : fmaxf(vy[0], oy0.x);
  vy[1] = kl ? fminf(vy[1], oy0.y) : fmaxf(vy[1], oy0.y);
  vy[2] = kl ? fminf(vy[2], oy0.z) : fmaxf(vy[2], oy0.z);
  vy[3] = kl ? fminf(vy[3], oy0.w) : fmaxf(vy[3], oy0.w);
  vy[4] = kl ? fminf(vy[4], oy1.x) : fmaxf(vy[4], oy1.x);
  vy[5] = kl ? fminf(vy[5], oy1.y) : fmaxf(vy[5], oy1.y);
  vy[6] = kl ? fminf(vy[6], oy1.z) : fmaxf(vy[6], oy1.z);
  vy[7] = kl ? fminf(vy[7], oy1.w) : fmaxf(vy[7], oy1.w);
  __syncthreads();
}

__global__ __launch_bounds__(512)
void k_sortdiff(const float* __restrict__ PX, const float* __restrict__ PY,
                const float* __restrict__ sp, const double* __restrict__ dmean,
                float* __restrict__ bsum) {
  __shared__ float lx[NSAMP];
  __shared__ float ly[NSAMP];
  __shared__ float red[8];
  const int bp = blockIdx.x;          // b*128 + p
  const int p = bp & (NPROJ - 1);
  const int t = threadIdx.x;
  const int ib = t * 8;

  float vx[8], vy[8];
  {
    const float4* rx = (const float4*)(PX + (size_t)bp * NSAMP) + t * 2;
    const float4* ry = (const float4*)(PY + (size_t)bp * NSAMP) + t * 2;
    float4 x0 = rx[0], x1 = rx[1], y0 = ry[0], y1 = ry[1];
    vx[0]=x0.x; vx[1]=x0.y; vx[2]=x0.z; vx[3]=x0.w;
    vx[4]=x1.x; vx[5]=x1.y; vx[6]=x1.z; vx[7]=x1.w;
    vy[0]=y0.x; vy[1]=y0.y; vy[2]=y0.z; vy[3]=y0.w;
    vy[4]=y1.x; vy[5]=y1.y; vy[6]=y1.z; vy[7]=y1.w;
  }

  // k=2,4,8 fully in-register
  {
    const bool u8 = ((t & 1) == 0);
    PHASEA(vx, u8);
    PHASEA(vy, u8);
  }

  // k=16..512: in-wave merges (shuffles + registers), no barriers
  merge_inwave<16>(vx, vy, t, ib);
  merge_inwave<32>(vx, vy, t, ib);
  merge_inwave<64>(vx, vy, t, ib);
  merge_inwave<128>(vx, vy, t, ib);
  merge_inwave<256>(vx, vy, t, ib);
  merge_inwave<512>(vx, vy, t, ib);

  // k=1024: one LDS stage (j=512), then in-wave
  {
    const bool up = ((ib & 1024) == 0);
    lds_stage(vx, vy, lx, ly, t, 512 >> 3, up);
    merge_inwave<1024>(vx, vy, t, ib);
  }
  // k=2048: LDS j=1024,512, then in-wave
  {
    const bool up = ((ib & 2048) == 0);
    lds_stage(vx, vy, lx, ly, t, 1024 >> 3, up);
    lds_stage(vx, vy, lx, ly, t, 512 >> 3, up);
    merge_inwave<2048>(vx, vy, t, ib);
  }
  // k=4096 (final, ascending): LDS j=2048,1024,512, then in-wave
  {
    const bool up = true;
    lds_stage(vx, vy, lx, ly, t, 2048 >> 3, up);
    lds_stage(vx, vy, lx, ly, t, 1024 >> 3, up);
    lds_stage(vx, vy, lx, ly, t, 512 >> 3, up);
    merge_inwave<4096>(vx, vy, t, ib);
  }

  // diff + reduce (register-local)
  const float delta = (float)(dmean[0]) * sp[p];
  float s = 0.f;
#pragma unroll
  for (int r = 0; r < 8; ++r) s += fabsf(vx[r] - vy[r] - delta);

#pragma unroll
  for (int o = 1; o < 64; o <<= 1) s += __shfl_xor(s, o, 64);
  if ((t & 63) == 0) red[t >> 6] = s;
  __syncthreads();
  if (t == 0) {
    float tot = 0.f;
#pragma unroll
    for (int i = 0; i < 8; ++i) tot += red[i];
    bsum[bp] = tot;
  }
}

// ---------------- kernel D: deterministic final reduce --------------------
__global__ void k_final(const float* __restrict__ bsum, float* __restrict__ out) {
  __shared__ double s[256];
  const int tid = threadIdx.x;
  double v = 0.0;
  for (int q = tid; q < BATCH * NPROJ; q += 256) v += (double)bsum[q];
  s[tid] = v;
  __syncthreads();
  for (int off = 128; off; off >>= 1) {
    if (tid < off) s[tid] += s[tid + off];
    __syncthreads();
  }
  if (tid == 0) out[0] = (float)(s[0] / ((double)NSAMP * NPROJ * BATCH));
}

extern "C" void kernel_launch(void* const* d_in, const int* in_sizes, int n_in,
                              void* d_out, int out_size, void* d_ws, size_t ws_size,
                              hipStream_t stream) {
  const float* x    = (const float*)d_in[0];
  const float* y    = (const float*)d_in[1];
  const float* proj = (const float*)d_in[2];
  const int* idx_x  = (const int*)d_in[3];
  const int* idx_y  = (const int*)d_in[4];
  float* out = (float*)d_out;

  char* ws = (char*)d_ws;
  double* pAx   = (double*)(ws + 0);        // 256 doubles
  double* pAy   = (double*)(ws + 2048);     // 256 doubles
  double* dmean = (double*)(ws + 4096);     // 1 double
  float*  sp    = (float*)(ws + 4160);      // 128 floats
  float*  bsum  = (float*)(ws + 8192);      // 2048 floats
  float*  PX    = (float*)(ws + 16384);     // 16*128*4096 floats
  float*  PY    = PX + (size_t)BATCH * NPROJ * NSAMP;

  const size_t need = 16384 + 2ull * BATCH * NPROJ * NSAMP * sizeof(float);
  if (ws_size < need) return;

  k_wsum    <<<256, 256, 0, stream>>>(x, y, pAx, pAy);
  k_meandiff<<<1, 256, 0, stream>>>(pAx, pAy, dmean);
  k_colsum  <<<1, NPROJ, 0, stream>>>(proj, sp);
  k_proj    <<<dim3(NSAMP / TM, BATCH, 2), 256, 0, stream>>>(x, y, proj, idx_x, idx_y, PX, PY);
  k_sortdiff<<<BATCH * NPROJ, 512, 0, stream>>>(PX, PY, sp, dmean, bsum);
  k_final   <<<1, 256, 0, stream>>>(bsum, out);
}

// Round 4
// 251.058 us; speedup vs baseline: 1.7049x; 1.0608x over previous
//
#include <hip/hip_runtime.h>
#include <cstddef>
#include <cstdint>

#define BATCH 16
#define CHAN 3
#define HH 128
#define WW 128
#define PATCHK 7
#define HP 122                 // (128-7)/1 + 1
#define PDIM 147               // 3*7*7
#define NSAMP 4096
#define NPROJ 128
#define IMG_PIX (CHAN*HH*WW)   // 49152
#define TOT_PIX (BATCH*IMG_PIX)
#define COUNT_D ((double)BATCH*HP*HP*PDIM)   // 35007168

// ---------------- kernel A: weighted pixel sums (patch-tensor mean) -------
__global__ __launch_bounds__(256)
void k_wsum(const float* __restrict__ x, const float* __restrict__ y,
            double* __restrict__ outx, double* __restrict__ outy) {
  float sx = 0.f, sy = 0.f;
  const int stride = gridDim.x * blockDim.x;
  for (int e = blockIdx.x * blockDim.x + threadIdx.x; e < TOT_PIX; e += stride) {
    int j = e & (WW - 1);
    int i = (e >> 7) & (HH - 1);
    int wi = min(i, HP - 1) - max(0, i - (PATCHK - 1)) + 1;
    int wj = min(j, HP - 1) - max(0, j - (PATCHK - 1)) + 1;
    float w = (float)(wi * wj);
    sx = fmaf(x[e], w, sx);
    sy = fmaf(y[e], w, sy);
  }
  __shared__ float rx[256], ry[256];
  const int tid = threadIdx.x;
  rx[tid] = sx; ry[tid] = sy;
  __syncthreads();
  for (int off = 128; off; off >>= 1) {
    if (tid < off) { rx[tid] += rx[tid + off]; ry[tid] += ry[tid + off]; }
    __syncthreads();
  }
  if (tid == 0) { outx[blockIdx.x] = (double)rx[0]; outy[blockIdx.x] = (double)ry[0]; }
}

// mean diff + proj column sums fused (both tiny, one launch)
__global__ void k_meandiff(const double* __restrict__ px, const double* __restrict__ py,
                           double* __restrict__ dmean,
                           const float* __restrict__ proj, float* __restrict__ sp) {
  const int tid = threadIdx.x;
  if (tid < NPROJ) {
    float s = 0.f;
    for (int d = 0; d < PDIM; ++d) s += proj[d * NPROJ + tid];
    sp[tid] = s;
  }
  __shared__ double sd[256];
  sd[tid] = px[tid] - py[tid];
  __syncthreads();
  for (int off = 128; off; off >>= 1) {
    if (tid < off) sd[tid] += sd[tid + off];
    __syncthreads();
  }
  if (tid == 0) dmean[0] = sd[0] / COUNT_D;
}

// ---------------- kernel B: gather + projection GEMM ----------------------
// TM=64, LDS 38.2KB -> 4 blocks/CU. Wave w owns p-block [32w,32w+32):
// proj values wave-uniform -> SGPR, explicitly double-buffered (bA/bB)
// so s_loads for k+1/k+2 issue before the FMAs of k.
#define TM 64
#define ASTR (TM + 1)
__device__ __forceinline__ void loadb(float (&dst)[32], const float* bp, int kk) {
#pragma unroll
  for (int pp = 0; pp < 32; ++pp) dst[pp] = bp[kk * NPROJ + pp];
}
__device__ __forceinline__ void fma32(float a, const float (&b)[32], float (&acc)[32]) {
#pragma unroll
  for (int pp = 0; pp < 32; ++pp) acc[pp] = fmaf(a, b[pp], acc[pp]);
}

__global__ __launch_bounds__(256)
void k_proj(const float* __restrict__ x, const float* __restrict__ y,
            const float* __restrict__ proj,
            const int* __restrict__ idx_x, const int* __restrict__ idx_y,
            float* __restrict__ PX, float* __restrict__ PY) {
  __shared__ float As[PDIM * ASTR];

  const int z = blockIdx.z;
  const float* im = z ? y : x;
  const int* idx = z ? idx_y : idx_x;
  float* dst = z ? PY : PX;
  const int b = blockIdx.y;
  const int nbase = blockIdx.x * TM;
  const int tid = threadIdx.x;

  const float* imb = im + b * IMG_PIX;
  for (int e = tid; e < TM * PDIM; e += 256) {
    int n = e / PDIM;
    int d = e - n * PDIM;
    int l = idx[nbase + n];
    int h0 = l / HP;
    int w0 = l - h0 * HP;
    int c  = d / 49;                   // d = c*49 + kh*7 + kw (channel-major)
    int r  = d - c * 49;
    int kh = r / 7;
    int kw = r - kh * 7;
    As[d * ASTR + n] = imb[(c * HH + h0 + kh) * WW + w0 + kw];
  }
  __syncthreads();

  const int lane = tid & 63;
  const int w = __builtin_amdgcn_readfirstlane(tid >> 6);
  const float* bp = proj + w * 32;

  float acc[32];
#pragma unroll
  for (int pp = 0; pp < 32; ++pp) acc[pp] = 0.f;

  float bA[32], bB[32];
  loadb(bA, bp, 0);
  for (int k = 0; k + 2 < PDIM; k += 2) {   // k = 0,2,...,144
    loadb(bB, bp, k + 1);
    const float a0 = As[k * ASTR + lane];
    const float a1 = As[(k + 1) * ASTR + lane];
    fma32(a0, bA, acc);
    loadb(bA, bp, k + 2);
    fma32(a1, bB, acc);
  }
  { // tail k = 146 (bA holds it from the last iteration's prefetch)
    const float a = As[146 * ASTR + lane];
    fma32(a, bA, acc);
  }

#pragma unroll
  for (int pp = 0; pp < 32; ++pp)
    dst[(size_t)(b * NPROJ + w * 32 + pp) * NSAMP + nbase + lane] = acc[pp];
}

// ---------------- kernel C: sign-flip bitonic sort + |diff| ---------------
// Invariant: entering merge K, register values are XORed with
// m_K = sign iff (i & K) != 0.  Every merge is then a PURE ASCENDING
// network: literal min/max in registers, merge-independent keepLo masks
// for cross-lane stages, 8 XOR/array transition between merges.
__device__ __forceinline__ float xorf(float v, unsigned m) {
  return __int_as_float(__float_as_int(v) ^ (int)m);
}
// ascending compare-exchange: a=min, b=max (2 VALU, no select)
#define CSW(a, b) { float _t = fminf(a, b); b = fmaxf(a, b); a = _t; }

// full ascending-directions bitonic sort of 8 (literal network, 24 comparators)
#define SORT8A(v) do { \
  CSW(v[0],v[1]); CSW(v[3],v[2]); CSW(v[4],v[5]); CSW(v[7],v[6]); \
  CSW(v[0],v[2]); CSW(v[1],v[3]); CSW(v[6],v[4]); CSW(v[7],v[5]); \
  CSW(v[0],v[1]); CSW(v[2],v[3]); CSW(v[5],v[4]); CSW(v[7],v[6]); \
  CSW(v[0],v[4]); CSW(v[1],v[5]); CSW(v[2],v[6]); CSW(v[3],v[7]); \
  CSW(v[0],v[2]); CSW(v[1],v[3]); CSW(v[4],v[6]); CSW(v[5],v[7]); \
  CSW(v[0],v[1]); CSW(v[2],v[3]); CSW(v[4],v[5]); CSW(v[6],v[7]); } while (0)

// ascending bitonic merge j=4,2,1 on the thread's 8 registers
#define REG3A(v) do { \
  CSW(v[0],v[4]); CSW(v[1],v[5]); CSW(v[2],v[6]); CSW(v[3],v[7]); \
  CSW(v[0],v[2]); CSW(v[1],v[3]); CSW(v[4],v[6]); CSW(v[5],v[7]); \
  CSW(v[0],v[1]); CSW(v[2],v[3]); CSW(v[4],v[5]); CSW(v[6],v[7]); } while (0)

#define FLIP8(v, m) { v[0]=xorf(v[0],m); v[1]=xorf(v[1],m); v[2]=xorf(v[2],m); \
  v[3]=xorf(v[3],m); v[4]=xorf(v[4],m); v[5]=xorf(v[5],m); v[6]=xorf(v[6],m); \
  v[7]=xorf(v[7],m); }

template <int DL>
__device__ __forceinline__ float swzxor(float v) {
  if constexpr (DL <= 16) {
    // ds_swizzle bit-mode: lane -> lane^DL within 32-lane group (no addr VALU)
    return __int_as_float(
        __builtin_amdgcn_ds_swizzle(__float_as_int(v), (DL << 10) | 0x1F));
  } else {
    return __shfl_xor(v, DL, 64);
  }
}

template <int DL>
__device__ __forceinline__ void shufxy(float (&vx)[8], float (&vy)[8], bool keepLo) {
#pragma unroll
  for (int r = 0; r < 8; ++r) {
    float ox = swzxor<DL>(vx[r]);
    vx[r] = keepLo ? fminf(vx[r], ox) : fmaxf(vx[r], ox);
    float oy = swzxor<DL>(vy[r]);
    vy[r] = keepLo ? fminf(vy[r], oy) : fmaxf(vy[r], oy);
  }
}

__device__ __forceinline__ void lds_stage(float (&vx)[8], float (&vy)[8],
                                          float* lx, float* ly, int t, int dl, bool kl) {
  ((float4*)lx)[t * 2]     = make_float4(vx[0], vx[1], vx[2], vx[3]);
  ((float4*)lx)[t * 2 + 1] = make_float4(vx[4], vx[5], vx[6], vx[7]);
  ((float4*)ly)[t * 2]     = make_float4(vy[0], vy[1], vy[2], vy[3]);
  ((float4*)ly)[t * 2 + 1] = make_float4(vy[4], vy[5], vy[6], vy[7]);
  __syncthreads();
  const int pt = (t ^ dl) * 2;
  float4 ox0 = ((const float4*)lx)[pt], ox1 = ((const float4*)lx)[pt + 1];
  float4 oy0 = ((const float4*)ly)[pt], oy1 = ((const float4*)ly)[pt + 1];
  vx[0] = kl ? fminf(vx[0], ox0.x) : fmaxf(vx[0], ox0.x);
  vx[1] = kl ? fminf(vx[1], ox0.y) : fmaxf(vx[1], ox0.y);
  vx[2] = kl ? fminf(vx[2], ox0.z) : fmaxf(vx[2], ox0.z);
  vx[3] = kl ? fminf(vx[3], ox0.w) : fmaxf(vx[3], ox0.w);
  vx[4] = kl ? fminf(vx[4], ox1.x) : fmaxf(vx[4], ox1.x);
  vx[5] = kl ? fminf(vx[5], ox1.y) : fmaxf(vx[5], ox1.y);
  vx[6] = kl ? fminf(vx[6], ox1.z) : fmaxf(vx[6], ox1.z);
  vx[7] = kl ? fminf(vx[7], ox1.w) : fmaxf(vx[7], ox1.w);
  vy[0] = kl ? fminf(vy[0], oy0.x) : fmaxf(vy[0], oy0.x);
  vy[1] = kl ? fminf(vy[1], oy0.y) : fmaxf(vy[1], oy0.y);
  vy[2] = kl ? fminf(vy[2], oy0.z) : fmaxf(vy[2], oy0.z);
  vy[3] = kl ? fminf(vy[3], oy0.w) : fmaxf(vy[3], oy0.w);
  vy[4] = kl ? fminf(vy[4], oy1.x) : fmaxf(vy[4], oy1.x);
  vy[5] = kl ? fminf(vy[5], oy1.y) : fmaxf(vy[5], oy1.y);
  vy[6] = kl ? fminf(vy[6], oy1.z) : fmaxf(vy[6], oy1.z);
  vy[7] = kl ? fminf(vy[7], oy1.w) : fmaxf(vy[7], oy1.w);
  __syncthreads();
}

__global__ __launch_bounds__(512)
void k_sortdiff(const float* __restrict__ PX, const float* __restrict__ PY,
                const float* __restrict__ sp, const double* __restrict__ dmean,
                float* __restrict__ bsum) {
  __shared__ float lx[NSAMP];
  __shared__ float ly[NSAMP];
  __shared__ float red[8];
  const int bp = blockIdx.x;          // b*128 + p
  const int p = bp & (NPROJ - 1);
  const unsigned t = threadIdx.x;

  // Gray-code transition masks: delta_K = m_K ^ m_2K (sign bit iff bits differ)
  const unsigned g = t ^ (t >> 1);
  const unsigned mA    = (t & 1u)   << 31;   // phase-A direction (i&8)
  const unsigned dA16  = (g & 1u)   << 31;   // mA ^ m16
  const unsigned d16   = (g & 2u)   << 30;
  const unsigned d32   = (g & 4u)   << 29;
  const unsigned d64   = (g & 8u)   << 28;
  const unsigned d128  = (g & 16u)  << 27;
  const unsigned d256  = (g & 32u)  << 26;
  const unsigned d512  = (g & 64u)  << 25;
  const unsigned d1024 = (g & 128u) << 24;
  const unsigned d2048 = (t & 256u) << 23;   // m2048 ^ m4096, m4096 = 0

  // merge-independent keepLo masks (ascending domain)
  const bool k1  = (t & 1u)  == 0, k2  = (t & 2u)  == 0, k4 = (t & 4u) == 0;
  const bool k8  = (t & 8u)  == 0, k16 = (t & 16u) == 0, k32 = (t & 32u) == 0;
  const bool kl64 = (t & 64u) == 0, kl128 = (t & 128u) == 0, kl256 = (t & 256u) == 0;

  float vx[8], vy[8];
  {
    const float4* rx = (const float4*)(PX + (size_t)bp * NSAMP) + t * 2;
    const float4* ry = (const float4*)(PY + (size_t)bp * NSAMP) + t * 2;
    float4 x0 = rx[0], x1 = rx[1], y0 = ry[0], y1 = ry[1];
    vx[0]=x0.x; vx[1]=x0.y; vx[2]=x0.z; vx[3]=x0.w;
    vx[4]=x1.x; vx[5]=x1.y; vx[6]=x1.z; vx[7]=x1.w;
    vy[0]=y0.x; vy[1]=y0.y; vy[2]=y0.z; vy[3]=y0.w;
    vy[4]=y1.x; vy[5]=y1.y; vy[6]=y1.z; vy[7]=y1.w;
  }

  // phase A: flip by mA, sort 8 ascending (all-literal), move to m16 domain
  FLIP8(vx, mA); FLIP8(vy, mA);
  SORT8A(vx); SORT8A(vy);
  FLIP8(vx, dA16); FLIP8(vy, dA16);

  // K=16
  shufxy<1>(vx, vy, k1); REG3A(vx); REG3A(vy);
  FLIP8(vx, d16); FLIP8(vy, d16);
  // K=32
  shufxy<2>(vx, vy, k2); shufxy<1>(vx, vy, k1); REG3A(vx); REG3A(vy);
  FLIP8(vx, d32); FLIP8(vy, d32);
  // K=64
  shufxy<4>(vx, vy, k4); shufxy<2>(vx, vy, k2); shufxy<1>(vx, vy, k1);
  REG3A(vx); REG3A(vy);
  FLIP8(vx, d64); FLIP8(vy, d64);
  // K=128
  shufxy<8>(vx, vy, k8); shufxy<4>(vx, vy, k4); shufxy<2>(vx, vy, k2);
  shufxy<1>(vx, vy, k1); REG3A(vx); REG3A(vy);
  FLIP8(vx, d128); FLIP8(vy, d128);
  // K=256
  shufxy<16>(vx, vy, k16); shufxy<8>(vx, vy, k8); shufxy<4>(vx, vy, k4);
  shufxy<2>(vx, vy, k2); shufxy<1>(vx, vy, k1); REG3A(vx); REG3A(vy);
  FLIP8(vx, d256); FLIP8(vy, d256);
  // K=512
  shufxy<32>(vx, vy, k32); shufxy<16>(vx, vy, k16); shufxy<8>(vx, vy, k8);
  shufxy<4>(vx, vy, k4); shufxy<2>(vx, vy, k2); shufxy<1>(vx, vy, k1);
  REG3A(vx); REG3A(vy);
  FLIP8(vx, d512); FLIP8(vy, d512);
  // K=1024
  lds_stage(vx, vy, lx, ly, (int)t, 64, kl64);
  shufxy<32>(vx, vy, k32); shufxy<16>(vx, vy, k16); shufxy<8>(vx, vy, k8);
  shufxy<4>(vx, vy, k4); shufxy<2>(vx, vy, k2); shufxy<1>(vx, vy, k1);
  REG3A(vx); REG3A(vy);
  FLIP8(vx, d1024); FLIP8(vy, d1024);
  // K=2048
  lds_stage(vx, vy, lx, ly, (int)t, 128, kl128);
  lds_stage(vx, vy, lx, ly, (int)t, 64, kl64);
  shufxy<32>(vx, vy, k32); shufxy<16>(vx, vy, k16); shufxy<8>(vx, vy, k8);
  shufxy<4>(vx, vy, k4); shufxy<2>(vx, vy, k2); shufxy<1>(vx, vy, k1);
  REG3A(vx); REG3A(vy);
  FLIP8(vx, d2048); FLIP8(vy, d2048);
  // K=4096 (final, real domain, ascending)
  lds_stage(vx, vy, lx, ly, (int)t, 256, kl256);
  lds_stage(vx, vy, lx, ly, (int)t, 128, kl128);
  lds_stage(vx, vy, lx, ly, (int)t, 64, kl64);
  shufxy<32>(vx, vy, k32); shufxy<16>(vx, vy, k16); shufxy<8>(vx, vy, k8);
  shufxy<4>(vx, vy, k4); shufxy<2>(vx, vy, k2); shufxy<1>(vx, vy, k1);
  REG3A(vx); REG3A(vy);

  // diff + reduce (register-local)
  const float delta = (float)(dmean[0]) * sp[p];
  float s = 0.f;
#pragma unroll
  for (int r = 0; r < 8; ++r) s += fabsf(vx[r] - vy[r] - delta);

#pragma unroll
  for (int o = 1; o < 64; o <<= 1) s += __shfl_xor(s, o, 64);
  if ((t & 63u) == 0) red[t >> 6] = s;
  __syncthreads();
  if (t == 0) {
    float tot = 0.f;
#pragma unroll
    for (int i = 0; i < 8; ++i) tot += red[i];
    bsum[bp] = tot;
  }
}

// ---------------- kernel D: deterministic final reduce --------------------
__global__ void k_final(const float* __restrict__ bsum, float* __restrict__ out) {
  __shared__ double s[256];
  const int tid = threadIdx.x;
  double v = 0.0;
  for (int q = tid; q < BATCH * NPROJ; q += 256) v += (double)bsum[q];
  s[tid] = v;
  __syncthreads();
  for (int off = 128; off; off >>= 1) {
    if (tid < off) s[tid] += s[tid + off];
    __syncthreads();
  }
  if (tid == 0) out[0] = (float)(s[0] / ((double)NSAMP * NPROJ * BATCH));
}

extern "C" void kernel_launch(void* const* d_in, const int* in_sizes, int n_in,
                              void* d_out, int out_size, void* d_ws, size_t ws_size,
                              hipStream_t stream) {
  const float* x    = (const float*)d_in[0];
  const float* y    = (const float*)d_in[1];
  const float* proj = (const float*)d_in[2];
  const int* idx_x  = (const int*)d_in[3];
  const int* idx_y  = (const int*)d_in[4];
  float* out = (float*)d_out;

  char* ws = (char*)d_ws;
  double* pAx   = (double*)(ws + 0);        // 256 doubles
  double* pAy   = (double*)(ws + 2048);     // 256 doubles
  double* dmean = (double*)(ws + 4096);     // 1 double
  float*  sp    = (float*)(ws + 4160);      // 128 floats
  float*  bsum  = (float*)(ws + 8192);      // 2048 floats
  float*  PX    = (float*)(ws + 16384);     // 16*128*4096 floats
  float*  PY    = PX + (size_t)BATCH * NPROJ * NSAMP;

  const size_t need = 16384 + 2ull * BATCH * NPROJ * NSAMP * sizeof(float);
  if (ws_size < need) return;

  k_wsum    <<<256, 256, 0, stream>>>(x, y, pAx, pAy);
  k_meandiff<<<1, 256, 0, stream>>>(pAx, pAy, dmean, proj, sp);
  k_proj    <<<dim3(NSAMP / TM, BATCH, 2), 256, 0, stream>>>(x, y, proj, idx_x, idx_y, PX, PY);
  k_sortdiff<<<BATCH * NPROJ, 512, 0, stream>>>(PX, PY, sp, dmean, bsum);
  k_final   <<<1, 256, 0, stream>>>(bsum, out);
}